// Round 1
// baseline (80.274 us; speedup 1.0000x reference)
//
#include <hip/hip_runtime.h>

#define H 128
#define STEPS 64
#define F_IN 33
#define R3H 384   // 3*H

// Single fused kernel: one block per step, 128 threads (= H).
// gh = W_hh @ h0 + b_hh is recomputed redundantly per block (thread j does
// rows j, j+128, j+256). W_hh is 196 KB -> fully L2-resident per XCD, so the
// redundant reads cost ~0.4 us aggregate and save a kernel launch + the
// workspace round-trip entirely.
__global__ __launch_bounds__(128) void Encoder_57380763074770_kernel(
    const float* __restrict__ x,        // [64,17]
    const int*   __restrict__ ip,       // [64,8]
    const int*   __restrict__ port,     // [64,2]
    const float* __restrict__ hidden,   // [128]
    const float* __restrict__ ip_emb,   // [256,1]
    const float* __restrict__ port_emb, // [70000,4]
    const float* __restrict__ W_ih,     // [384,33] row-major
    const float* __restrict__ W_hh,     // [384,128] row-major
    const float* __restrict__ b_ih,     // [384]
    const float* __restrict__ b_hh,     // [384]
    float* __restrict__ out)            // [64*128 + 128]
{
    __shared__ float xi[F_IN];
    __shared__ float h0s[H];
    __shared__ float wih[R3H * F_IN];   // 12672 floats = 50688 B

    const int s   = blockIdx.x;         // step
    const int tid = threadIdx.x;
    const int j   = tid;                // output column 0..127

    // stage xi = concat(x[s], ip_emb[ip[s]], port_emb[port[s]])
    if (tid < 17) {
        xi[tid] = x[s * 17 + tid];
    } else if (tid < 25) {
        xi[tid] = ip_emb[ip[s * 8 + (tid - 17)]];
    } else if (tid < F_IN) {
        int c = tid - 25;               // 0..7
        xi[tid] = port_emb[port[s * 2 + (c >> 2)] * 4 + (c & 3)];
    }
    h0s[tid] = hidden[tid];

    // stage W_ih into LDS, coalesced float4 (12672/4 = 3168 float4)
    {
        const float4* w4 = (const float4*)W_ih;
        float4*       l4 = (float4*)wih;
        #pragma unroll
        for (int i = 0; i < 25; ++i) {  // 25*128 = 3200 >= 3168
            int idx = tid + i * 128;
            if (idx < (R3H * F_IN) / 4) l4[idx] = w4[idx];
        }
    }

    // biases (L2-hot, coalesced) while staging drains
    float ghr = b_hh[j];
    float ghz = b_hh[j + H];
    float ghn = b_hh[j + 2 * H];
    float gir = b_ih[j];
    float giz = b_ih[j + H];
    float gin = b_ih[j + 2 * H];

    __syncthreads();                    // h0s, xi, wih ready

    // gh rows j, j+128, j+256: dot(W_hh[row], h0). Rows are 512 B apart,
    // 16B-aligned; per-thread contiguous float4 reads, all L2 hits after
    // first touch. h0 read from LDS is a 64-lane broadcast (conflict-free).
    {
        const float4* wr = (const float4*)(W_hh + (size_t)j * H);
        const float4* wz = (const float4*)(W_hh + (size_t)(j + H) * H);
        const float4* wn = (const float4*)(W_hh + (size_t)(j + 2 * H) * H);
        const float4* h4 = (const float4*)h0s;
        #pragma unroll 4
        for (int k = 0; k < H / 4; ++k) {
            const float4 hv = h4[k];
            const float4 ar = wr[k];
            const float4 az = wz[k];
            const float4 an = wn[k];
            ghr = fmaf(hv.x, ar.x, ghr);
            ghr = fmaf(hv.y, ar.y, ghr);
            ghr = fmaf(hv.z, ar.z, ghr);
            ghr = fmaf(hv.w, ar.w, ghr);
            ghz = fmaf(hv.x, az.x, ghz);
            ghz = fmaf(hv.y, az.y, ghz);
            ghz = fmaf(hv.z, az.z, ghz);
            ghz = fmaf(hv.w, az.w, ghz);
            ghn = fmaf(hv.x, an.x, ghn);
            ghn = fmaf(hv.y, an.y, ghn);
            ghn = fmaf(hv.z, an.z, ghn);
            ghn = fmaf(hv.w, an.w, ghn);
        }
    }

    // gi = xi @ W_ih^T + b_ih (LDS, stride-33 is bank-conflict-free)
    {
        const float* vr = wih + j * F_IN;
        const float* vz = wih + (j + H) * F_IN;
        const float* vn = wih + (j + 2 * H) * F_IN;
        #pragma unroll
        for (int k = 0; k < F_IN; ++k) {
            const float xv = xi[k];
            gir = fmaf(xv, vr[k], gir);
            giz = fmaf(xv, vz[k], giz);
            gin = fmaf(xv, vn[k], gin);
        }
    }

    const float r = 1.0f / (1.0f + __expf(-(gir + ghr)));
    const float z = 1.0f / (1.0f + __expf(-(giz + ghz)));
    float a = gin + r * ghn;
    a = fminf(fmaxf(a, -15.0f), 15.0f);
    const float e2 = __expf(2.0f * a);
    const float n = (e2 - 1.0f) / (e2 + 1.0f);
    const float o = (1.0f - z) * n + z * h0s[j];

    out[s * H + j] = o;
    if (s == STEPS - 1) out[STEPS * H + j] = o;   // new_hidden tail
}

extern "C" void kernel_launch(void* const* d_in, const int* in_sizes, int n_in,
                              void* d_out, int out_size, void* d_ws, size_t ws_size,
                              hipStream_t stream) {
    const float* x        = (const float*)d_in[0];
    const int*   ip       = (const int*)  d_in[1];
    const int*   port     = (const int*)  d_in[2];
    const float* hidden   = (const float*)d_in[3];
    const float* ip_emb   = (const float*)d_in[4];
    const float* port_emb = (const float*)d_in[5];
    const float* W_ih     = (const float*)d_in[6];
    const float* W_hh     = (const float*)d_in[7];
    const float* b_ih     = (const float*)d_in[8];
    const float* b_hh     = (const float*)d_in[9];
    float* out = (float*)d_out;
    (void)d_ws; (void)ws_size;          // workspace intentionally unused

    Encoder_57380763074770_kernel<<<STEPS, H, 0, stream>>>(
        x, ip, port, hidden, ip_emb, port_emb, W_ih, W_hh, b_ih, b_hh, out);
}